// Round 9
// baseline (317.742 us; speedup 1.0000x reference)
//
#include <hip/hip_runtime.h>
#include <hip/hip_bf16.h>

// GraphSAGE 2-layer forward on MI355X — round 9.
// Feature tensors live XCD-sliced: T[4][N][32] bf16 (slice = 32 cols = one
// 64B line per row). Aggregation binds slice->XCD (blockIdx&7 octant; 2
// octants per slice, splitting the node range) so each XCD's gather working
// set is a 3.2MB slice -> L2-resident. 16 lanes/edge, 4 edges per load
// instruction, 8 loads in flight. The sliced layout is exactly MFMA
// A-fragment order (k = kgrp*8 + kb*32 -> slice kb, offset kgrp*8), so GEMMs
// read it directly and gemm1 writes hT sliced — no repack kernels.
// deg_count is now XCD-partitioned like fill (atomic line ping-pong fix).

#define BLK 256

typedef __attribute__((ext_vector_type(8))) short short8;
typedef __attribute__((ext_vector_type(4))) float f32x4;

__device__ inline unsigned short f2bf(float f) {
    unsigned int u = __builtin_bit_cast(unsigned int, f);
    u += 0x7fffu + ((u >> 16) & 1u);  // RNE (inputs finite)
    return (unsigned short)(u >> 16);
}
__device__ inline float bf2f(unsigned short h) {
    return __builtin_bit_cast(float, ((unsigned int)h) << 16);
}

// ---------------- CSR build ----------------

// XCD-partitioned degree count: blockIdx&7 owns a dst octant so the atomicAdd
// target slice (~25KB) stays in one XCD's L2 (no cross-XCD line ping-pong).
__global__ __launch_bounds__(BLK) void deg_xcd_kernel(const int* __restrict__ dst, int E,
                                                      int* __restrict__ deg,
                                                      int range, int CH) {
    const int oct = blockIdx.x & 7;
    const int chunk = blockIdx.x >> 3;
    const int lo = oct * range, hi = lo + range;
    int e0 = chunk * CH;
    int e1 = min(E, e0 + CH);
    for (int e = e0 + threadIdx.x; e < e1; e += BLK) {
        int d = dst[e];
        if (d >= lo && d < hi) atomicAdd(&deg[d], 1);
    }
}

__global__ __launch_bounds__(BLK) void partial_sum_kernel(const int* __restrict__ deg,
                                                          int n, int* __restrict__ partials) {
    __shared__ int s[BLK];
    int t = threadIdx.x;
    int idx = blockIdx.x * BLK + t;
    s[t] = (idx < n) ? deg[idx] : 0;
    __syncthreads();
    for (int o = BLK / 2; o > 0; o >>= 1) {
        if (t < o) s[t] += s[t + o];
        __syncthreads();
    }
    if (t == 0) partials[blockIdx.x] = s[0];
}

__global__ __launch_bounds__(BLK) void scan_partials_kernel(int* __restrict__ partials, int n) {
    __shared__ int s[BLK];
    int t = threadIdx.x;
    int v = (t < n) ? partials[t] : 0;
    s[t] = v;
    __syncthreads();
    int sum = v;
    for (int o = 1; o < BLK; o <<= 1) {
        int other = (t >= o) ? s[t - o] : 0;
        __syncthreads();
        sum += other;
        s[t] = sum;
        __syncthreads();
    }
    if (t < n) partials[t] = sum - v;  // exclusive
}

__global__ __launch_bounds__(BLK) void chunk_scan_kernel(const int* __restrict__ deg,
                                                         const int* __restrict__ partials,
                                                         int n, int* __restrict__ row_start) {
    __shared__ int s[BLK];
    int t = threadIdx.x;
    int idx = blockIdx.x * BLK + t;
    int v = (idx < n) ? deg[idx] : 0;
    s[t] = v;
    __syncthreads();
    int sum = v;
    for (int o = 1; o < BLK; o <<= 1) {
        int other = (t >= o) ? s[t - o] : 0;
        __syncthreads();
        sum += other;
        s[t] = sum;
        __syncthreads();
    }
    if (idx < n) row_start[idx] = (sum - v) + partials[blockIdx.x];
}

// XCD-partitioned fill (proved out in rounds 5/8).
__global__ __launch_bounds__(BLK) void fill_xcd_kernel(const int* __restrict__ src,
                                                       const int* __restrict__ dst, int E,
                                                       const int* __restrict__ row_start,
                                                       int* __restrict__ cursor,
                                                       int* __restrict__ csr_src,
                                                       int range, int CH) {
    const int oct = blockIdx.x & 7;
    const int chunk = blockIdx.x >> 3;
    const int lo = oct * range, hi = lo + range;
    int e0 = chunk * CH;
    int e1 = min(E, e0 + CH);
    for (int e = e0 + threadIdx.x; e < e1; e += BLK) {
        int d = dst[e];
        if (d >= lo && d < hi) {
            int pos = atomicAdd(&cursor[d], 1);
            csr_src[row_start[d] + pos] = src[e];
        }
    }
}

// ---------------- prep: x -> sliced bf16 xT[4][N][32], + all W packs ----------------
// P[((kb*(Ncol/16)+n16)*64 + lane)*8 + j] = W[kb*32 + (lane>>4)*8 + j][n16*16 + (lane&15)]

__global__ __launch_bounds__(BLK) void prep_kernel(const float* __restrict__ x,
                                                   unsigned short* __restrict__ xT, int N,
                                                   const float* __restrict__ W1l,
                                                   const float* __restrict__ W1r,
                                                   const float* __restrict__ W2l,
                                                   const float* __restrict__ W2r,
                                                   unsigned short* __restrict__ P1l,
                                                   unsigned short* __restrict__ P1r,
                                                   unsigned short* __restrict__ P2l,
                                                   unsigned short* __restrict__ P2r) {
    int t = blockIdx.x * BLK + threadIdx.x;
    const int NX = N * 4;
    if (t < NX) {
        int node = t >> 2, slice = t & 3;
        const float4* xp = (const float4*)(x + (size_t)node * 128 + slice * 32);
        unsigned int u[16];
#pragma unroll
        for (int q = 0; q < 8; ++q) {
            float4 v = xp[q];
            u[q * 2]     = (unsigned int)f2bf(v.x) | ((unsigned int)f2bf(v.y) << 16);
            u[q * 2 + 1] = (unsigned int)f2bf(v.z) | ((unsigned int)f2bf(v.w) << 16);
        }
        uint4* o = (uint4*)(xT + ((size_t)slice * N + node) * 32);
#pragma unroll
        for (int q = 0; q < 4; ++q)
            o[q] = make_uint4(u[q * 4], u[q * 4 + 1], u[q * 4 + 2], u[q * 4 + 3]);
        return;
    }
    int w = t - NX;
    const float* W;
    unsigned short* P;
    int Ncol, local;
    if (w < 16384)      { W = W1l; P = P1l; Ncol = 128; local = w; }
    else if (w < 32768) { W = W1r; P = P1r; Ncol = 128; local = w - 16384; }
    else if (w < 40960) { W = W2l; P = P2l; Ncol = 64;  local = w - 32768; }
    else if (w < 49152) { W = W2r; P = P2r; Ncol = 64;  local = w - 40960; }
    else return;
    int j = local & 7;
    int lane = (local >> 3) & 63;
    int rest = local >> 9;
    int nt = Ncol >> 4;
    int n16 = rest % nt, kb = rest / nt;
    int k = kb * 32 + (lane >> 4) * 8 + j;
    int c = n16 * 16 + (lane & 15);
    P[local] = f2bf(W[(size_t)k * Ncol + c]);
}

// ---------------- sliced mean aggregation ----------------
// Octant oct=blockIdx&7 -> slice oct>>1, node-half oct&1 (slice<->XCD affinity,
// 3.2MB slice L2-resident per XCD). Wave = one node. 16 lanes per edge
// (cu=lane&15 -> uint col), sub=lane>>4 -> 4 edges per load instruction,
// unroll 8 -> 8 loads in flight. Per-lane weight (inv or 0) via cndmask.

__global__ __launch_bounds__(BLK) void agg4_kernel(const unsigned short* __restrict__ fT,
                                                   const int* __restrict__ row_start,
                                                   const int* __restrict__ deg,
                                                   const int* __restrict__ csr_src,
                                                   unsigned short* __restrict__ aT,
                                                   int N, int E) {
    const int wave = threadIdx.x >> 6, lane = threadIdx.x & 63;
    const int oct = blockIdx.x & 7;
    const int k = blockIdx.x >> 3;
    const int slice = oct >> 1, half = oct & 1;
    const int halfSize = (N + 1) >> 1;
    const int node = half * halfSize + k * 4 + wave;
    if (node >= N || node >= (half + 1) * halfSize) return;

    const int start = __builtin_amdgcn_readfirstlane(row_start[node]);
    int cnt = __builtin_amdgcn_readfirstlane(deg[node]);
    cnt = min(cnt, E);
    const float inv = 1.0f / fmaxf((float)cnt, 1.0f);

    const unsigned int* xs = (const unsigned int*)(fT + (size_t)slice * N * 32);  // [N][16]
    const int cu = lane & 15;
    const int sub = lane >> 4;

    float a0 = 0.f, a1 = 0.f;
    for (int base = 0; base < cnt; base += 64) {
        int m = cnt - base;
        if (m > 64) m = 64;
        int idxv = csr_src[start + base + (lane < m ? lane : m - 1)];
        for (int e = 0; e < m; e += 32) {
            unsigned int v[8];
            float wgt[8];
#pragma unroll
            for (int j = 0; j < 8; j++) {
                int slot = e + j * 4 + sub;
                wgt[j] = (slot < m) ? inv : 0.0f;
                int sl = slot < m ? slot : m - 1;
                int s = __shfl(idxv, sl);
                v[j] = xs[(size_t)s * 16 + cu];
            }
#pragma unroll
            for (int j = 0; j < 8; j++) {
                a0 = fmaf(bf2f((unsigned short)v[j]), wgt[j], a0);
                a1 = fmaf(bf2f((unsigned short)(v[j] >> 16)), wgt[j], a1);
            }
        }
    }
    a0 += __shfl_xor(a0, 16); a1 += __shfl_xor(a1, 16);
    a0 += __shfl_xor(a0, 32); a1 += __shfl_xor(a1, 32);
    if (sub == 0) {
        unsigned int* as = (unsigned int*)(aT + (size_t)slice * N * 32);
        as[(size_t)node * 16 + cu] = (unsigned int)f2bf(a0) | ((unsigned int)f2bf(a1) << 16);
    }
}

// ---------------- MFMA dual GEMM on sliced A operands ----------------
// A1,A2: [4][M][32] bf16 sliced. A-frag k = kgrp*8 + kb*32 -> plane kb,
// offset kgrp*8. OUTMODE 1: bf16 sliced [4][M][32]; OUTMODE 0: f32 row-major.

template <int NCOL, bool RELU, int OUTMODE>
__global__ __launch_bounds__(BLK) void gemm_dual_T_kernel(const unsigned short* __restrict__ A1,
                                                          const unsigned short* __restrict__ A2,
                                                          const unsigned short* __restrict__ Pl,
                                                          const unsigned short* __restrict__ Pr,
                                                          const float* __restrict__ bias,
                                                          void* __restrict__ outp, int M) {
    constexpr int NT = NCOL / 16;
    const int wave = threadIdx.x >> 6, lane = threadIdx.x & 63;
    const int r0 = blockIdx.x * 128 + wave * 32;
    const int arow = lane & 15, kgrp = lane >> 4;

    f32x4 acc[2][NT];
#pragma unroll
    for (int h = 0; h < 2; h++)
#pragma unroll
        for (int n = 0; n < NT; n++) acc[h][n] = (f32x4){0.f, 0.f, 0.f, 0.f};

    const int ra = min(r0 + arow, M - 1);
    const int rb = min(r0 + 16 + arow, M - 1);
    const size_t plane = (size_t)M * 32;

#pragma unroll
    for (int mat = 0; mat < 2; ++mat) {
        const unsigned short* A = mat ? A2 : A1;
        const unsigned short* P = mat ? Pr : Pl;
        const unsigned short* Aa = A + (size_t)ra * 32 + kgrp * 8;
        const unsigned short* Ab = A + (size_t)rb * 32 + kgrp * 8;
#pragma unroll
        for (int kb = 0; kb < 4; ++kb) {
            short8 afa = *(const short8*)(Aa + (size_t)kb * plane);
            short8 afb = *(const short8*)(Ab + (size_t)kb * plane);
            const unsigned short* Pk = P + (size_t)kb * NT * 512 + lane * 8;
#pragma unroll
            for (int n = 0; n < NT; ++n) {
                short8 wf = *(const short8*)(Pk + n * 512);
                acc[0][n] = __builtin_amdgcn_mfma_f32_16x16x32_bf16(afa, wf, acc[0][n], 0, 0, 0);
                acc[1][n] = __builtin_amdgcn_mfma_f32_16x16x32_bf16(afb, wf, acc[1][n], 0, 0, 0);
            }
        }
    }

    // D layout: col = n*16 + arow, row = r0 + h*16 + kgrp*4 + i
#pragma unroll
    for (int n = 0; n < NT; ++n) {
        int col = n * 16 + arow;
        float bv = bias[col];
#pragma unroll
        for (int h = 0; h < 2; ++h) {
#pragma unroll
            for (int i = 0; i < 4; ++i) {
                int row = r0 + h * 16 + kgrp * 4 + i;
                if (row < M) {
                    float v = acc[h][n][i] + bv;
                    if (RELU) v = fmaxf(v, 0.f);
                    if (OUTMODE == 1) {
                        int sl = col >> 5, c32 = col & 31;
                        ((unsigned short*)outp)[(size_t)sl * M * 32 + (size_t)row * 32 + c32] =
                            f2bf(v);
                    } else {
                        ((float*)outp)[(size_t)row * NCOL + col] = v;
                    }
                }
            }
        }
    }
}

// ---------------- launch ----------------

extern "C" void kernel_launch(void* const* d_in, const int* in_sizes, int n_in,
                              void* d_out, int out_size, void* d_ws, size_t ws_size,
                              hipStream_t stream) {
    const float* x   = (const float*)d_in[0];
    const int*   ei  = (const int*)d_in[1];
    const float* W1l = (const float*)d_in[2];
    const float* W1r = (const float*)d_in[3];
    const float* b1  = (const float*)d_in[4];
    const float* W2l = (const float*)d_in[5];
    const float* W2r = (const float*)d_in[6];
    const float* b2  = (const float*)d_in[7];
    float* out = (float*)d_out;

    const int N = in_sizes[0] / 128;  // 50000
    const int E = in_sizes[1] / 2;    // 800000
    const int* src = ei;
    const int* dst = ei + E;

    char* ws = (char*)d_ws;
    size_t off = 0;
    auto carve = [&](size_t bytes) {
        void* p = ws + off;
        off += (bytes + 255) & ~(size_t)255;
        return p;
    };
    int* deg       = (int*)carve((size_t)2 * N * 4);  // deg + cursor, one memset
    int* cursor    = deg + N;
    int* row_start = (int*)carve((size_t)N * 4);
    int* partials  = (int*)carve(256 * 4);
    int* csr_src   = (int*)carve((size_t)E * 4);
    unsigned short* xT   = (unsigned short*)carve((size_t)4 * N * 32 * 2);  // [4][N][32]
    unsigned short* hT   = (unsigned short*)carve((size_t)4 * N * 32 * 2);
    unsigned short* aggT = (unsigned short*)carve((size_t)4 * N * 32 * 2);
    unsigned short* P1l  = (unsigned short*)carve(128 * 128 * 2);
    unsigned short* P1r  = (unsigned short*)carve(128 * 128 * 2);
    unsigned short* P2l  = (unsigned short*)carve(128 * 64 * 2);
    unsigned short* P2r  = (unsigned short*)carve(128 * 64 * 2);

    hipMemsetAsync(deg, 0, (size_t)2 * N * 4, stream);

    // prep: x -> xT sliced + all W packs, one dispatch
    const int prepThreads = N * 4 + 49152;
    prep_kernel<<<(prepThreads + BLK - 1) / BLK, BLK, 0, stream>>>(
        x, xT, N, W1l, W1r, W2l, W2r, P1l, P1r, P2l, P2r);

    // CSR build (deg + fill XCD-partitioned)
    const int range = (N + 7) / 8;          // 6250
    const int NCHUNKS = 512;
    const int CH = (E + NCHUNKS - 1) / NCHUNKS;
    deg_xcd_kernel<<<8 * NCHUNKS, BLK, 0, stream>>>(dst, E, deg, range, CH);

    const int nchunk = (N + BLK - 1) / BLK;  // 196 (<=256)
    partial_sum_kernel<<<nchunk, BLK, 0, stream>>>(deg, N, partials);
    scan_partials_kernel<<<1, BLK, 0, stream>>>(partials, nchunk);
    chunk_scan_kernel<<<nchunk, BLK, 0, stream>>>(deg, partials, N, row_start);

    fill_xcd_kernel<<<8 * NCHUNKS, BLK, 0, stream>>>(src, dst, E, row_start, cursor,
                                                     csr_src, range, CH);

    // agg grid: oct = blockIdx&7 (slice = oct>>1, half = oct&1), 4 nodes/block
    const int halfSize = (N + 1) >> 1;
    const int aggGrid = 8 * ((halfSize + 3) / 4);
    const int gemmGrid = (N + 127) / 128;

    // layer 1: hT = relu(agg(x)@W1l + b1 + x@W1r)   (sliced bf16)
    agg4_kernel<<<aggGrid, BLK, 0, stream>>>(xT, row_start, deg, csr_src, aggT, N, E);
    gemm_dual_T_kernel<128, true, 1><<<gemmGrid, BLK, 0, stream>>>(aggT, xT, P1l, P1r, b1, hT, N);
    // layer 2: out = agg(h)@W2l + b2 + h@W2r        (f32 row-major)
    agg4_kernel<<<aggGrid, BLK, 0, stream>>>(hT, row_start, deg, csr_src, aggT, N, E);
    gemm_dual_T_kernel<64, false, 0><<<gemmGrid, BLK, 0, stream>>>(aggT, hT, P2l, P2r, b2, out, N);
}